// Round 1
// baseline (2510.759 us; speedup 1.0000x reference)
//
#include <hip/hip_runtime.h>
#include <cstdint>
#include <cstddef>

// Problem constants (B=4, S=2048 -> T=8192 tokens)
#define T_TOK 8192
#define H_DIM 1024
#define F_DIM 3584
#define E_NUM 8

typedef __bf16 bf16_t;
typedef bf16_t bf16x8 __attribute__((ext_vector_type(8)));
typedef bf16_t bf16x4 __attribute__((ext_vector_type(4)));
typedef float floatx4 __attribute__((ext_vector_type(4)));

typedef const __attribute__((address_space(1))) void* gas_ptr;
typedef __attribute__((address_space(3))) void* las_ptr;

// async global->LDS, 16B per lane. LDS dest is wave-uniform base + lane*16.
__device__ __forceinline__ void async_copy16(const void* g, void* l) {
    __builtin_amdgcn_global_load_lds((gas_ptr)g, (las_ptr)l, 16, 0, 0);
}

// ---------------- elementwise fp32 -> bf16 cast (4 elems/thread) ----------------
__global__ void cast_f32_to_bf16(const float* __restrict__ in, bf16_t* __restrict__ out, int n4) {
    int i = blockIdx.x * blockDim.x + threadIdx.x;
    if (i < n4) {
        const float4 v = ((const float4*)in)[i];
        bf16x4 o;
        o[0] = (bf16_t)v.x; o[1] = (bf16_t)v.y; o[2] = (bf16_t)v.z; o[3] = (bf16_t)v.w;
        ((bf16x4*)out)[i] = o;
    }
}

// ---------------- w2 [E,F,H] fp32 -> w2t [E,H,F] bf16 (tiled transpose) ----------------
__global__ void transpose_cast_w2(const float* __restrict__ W2, bf16_t* __restrict__ W2T) {
    __shared__ bf16_t tile[32][34];  // stride 34 bf16 = 17 words: conflict-free column reads
    const int e = blockIdx.z;
    const int f0 = blockIdx.x * 32;
    const int h0 = blockIdx.y * 32;
    const float* src = W2 + (size_t)e * F_DIM * H_DIM;
    bf16_t* dst = W2T + (size_t)e * H_DIM * F_DIM;
    const int tx = threadIdx.x;  // 0..31
    const int ty = threadIdx.y;  // 0..7
#pragma unroll
    for (int r = 0; r < 32; r += 8)
        tile[ty + r][tx] = (bf16_t)src[(size_t)(f0 + ty + r) * H_DIM + (h0 + tx)];
    __syncthreads();
#pragma unroll
    for (int r = 0; r < 32; r += 8)
        dst[(size_t)(h0 + ty + r) * F_DIM + (f0 + tx)] = tile[tx][ty + r];
}

// ---------------- router: fp32 logits -> softmax -> top-2 -> renorm coef[T,E] ----------------
__global__ void router_kernel(const float* __restrict__ X, const float* __restrict__ RW,
                              float* __restrict__ coef) {
    const int lane = threadIdx.x & 63;
    const int wave = threadIdx.x >> 6;
    const int t = blockIdx.x * 4 + wave;
    const float* xp = X + (size_t)t * H_DIM;
    float xr[16];
#pragma unroll
    for (int j = 0; j < 16; ++j) xr[j] = xp[j * 64 + lane];  // coalesced
    float logits[E_NUM];
#pragma unroll
    for (int e = 0; e < E_NUM; ++e) {
        const float* rp = RW + e * H_DIM;
        float a = 0.f;
#pragma unroll
        for (int j = 0; j < 16; ++j) a += xr[j] * rp[j * 64 + lane];
#pragma unroll
        for (int s = 32; s; s >>= 1) a += __shfl_xor(a, s, 64);
        logits[e] = a;
    }
    if (lane == 0) {
        float mx = logits[0];
#pragma unroll
        for (int e = 1; e < E_NUM; ++e) mx = fmaxf(mx, logits[e]);
        float p[E_NUM], sum = 0.f;
#pragma unroll
        for (int e = 0; e < E_NUM; ++e) { p[e] = __expf(logits[e] - mx); sum += p[e]; }
#pragma unroll
        for (int e = 0; e < E_NUM; ++e) p[e] /= sum;
        int i0 = 0;
#pragma unroll
        for (int e = 1; e < E_NUM; ++e) if (p[e] > p[i0]) i0 = e;  // ties -> lowest idx (matches top_k)
        int i1 = (i0 == 0) ? 1 : 0;
#pragma unroll
        for (int e = 0; e < E_NUM; ++e) if (e != i0 && p[e] > p[i1]) i1 = e;
        const float s2 = p[i0] + p[i1];
        float outc[E_NUM];
#pragma unroll
        for (int e = 0; e < E_NUM; ++e) outc[e] = 0.f;
        outc[i0] = p[i0] / s2;
        outc[i1] = p[i1] / s2;
#pragma unroll
        for (int e = 0; e < E_NUM; ++e) coef[(size_t)t * E_NUM + e] = outc[e];
    }
}

// ---------------- GEMM1 (dual-acc GLU): hmid = coef * silu(X@W1^T) * (X@V1^T) ----------------
// X [T,H] bf16 row-major, W1/V1 [F,H] bf16 (i.e. [N,K] = B^T format), hmid [T,F] bf16.
// 128x128 tile, BK=32, 256 threads = 4 waves in 2x2, each wave 64x64 (4x4 of 16x16x32 MFMA, dual acc).
__global__ __launch_bounds__(256, 2)
void gemm1_glu(const bf16_t* __restrict__ X, const bf16_t* __restrict__ W1,
               const bf16_t* __restrict__ V1, const float* __restrict__ coef,
               bf16_t* __restrict__ Hmid, int e) {
    __shared__ __attribute__((aligned(16))) bf16_t As[128 * 32];
    __shared__ __attribute__((aligned(16))) bf16_t B1s[128 * 32];
    __shared__ __attribute__((aligned(16))) bf16_t B2s[128 * 32];
    const int tid = threadIdx.x;
    const int lane = tid & 63;
    const int wave = tid >> 6;
    const int m0 = blockIdx.x * 128;
    const int n0 = blockIdx.y * 128;
    const int wm = (wave >> 1) * 64;
    const int wn = (wave & 1) * 64;
    const int fr = lane & 15;
    const int q = lane >> 4;

    floatx4 acc1[4][4], acc2[4][4];
    const floatx4 zero = {0.f, 0.f, 0.f, 0.f};
#pragma unroll
    for (int a = 0; a < 4; ++a)
#pragma unroll
        for (int b = 0; b < 4; ++b) { acc1[a][b] = zero; acc2[a][b] = zero; }

    // staging: chunk c = i*256 + tid; row = c>>2 (tile row), col-chunk = (c&3)*8 bf16
    const int srow = tid >> 2;
    const int scc = (tid & 3) * 8;
    const int ldsb0 = (tid & 192) * 16;        // wave-uniform byte base, i=0
    const int ldsb1 = 4096 + ldsb0;            // i=1

    for (int k0 = 0; k0 < H_DIM; k0 += 32) {
        const size_t kc = (size_t)(k0 + scc);
        async_copy16(X + (size_t)(m0 + srow) * H_DIM + kc, (char*)As + ldsb0);
        async_copy16(X + (size_t)(m0 + 64 + srow) * H_DIM + kc, (char*)As + ldsb1);
        async_copy16(W1 + (size_t)(n0 + srow) * H_DIM + kc, (char*)B1s + ldsb0);
        async_copy16(W1 + (size_t)(n0 + 64 + srow) * H_DIM + kc, (char*)B1s + ldsb1);
        async_copy16(V1 + (size_t)(n0 + srow) * H_DIM + kc, (char*)B2s + ldsb0);
        async_copy16(V1 + (size_t)(n0 + 64 + srow) * H_DIM + kc, (char*)B2s + ldsb1);
        __syncthreads();

        bf16x8 af[4], b1f[4], b2f[4];
#pragma unroll
        for (int mi = 0; mi < 4; ++mi)
            af[mi] = *(const bf16x8*)&As[(wm + mi * 16 + fr) * 32 + q * 8];
#pragma unroll
        for (int ni = 0; ni < 4; ++ni) {
            b1f[ni] = *(const bf16x8*)&B1s[(wn + ni * 16 + fr) * 32 + q * 8];
            b2f[ni] = *(const bf16x8*)&B2s[(wn + ni * 16 + fr) * 32 + q * 8];
        }
#pragma unroll
        for (int mi = 0; mi < 4; ++mi)
#pragma unroll
            for (int ni = 0; ni < 4; ++ni) {
                acc1[mi][ni] = __builtin_amdgcn_mfma_f32_16x16x32_bf16(af[mi], b1f[ni], acc1[mi][ni], 0, 0, 0);
                acc2[mi][ni] = __builtin_amdgcn_mfma_f32_16x16x32_bf16(af[mi], b2f[ni], acc2[mi][ni], 0, 0, 0);
            }
        __syncthreads();
    }

    // epilogue: C layout col = lane&15, row = q*4 + reg
#pragma unroll
    for (int mi = 0; mi < 4; ++mi) {
#pragma unroll
        for (int r = 0; r < 4; ++r) {
            const int row = m0 + wm + mi * 16 + q * 4 + r;
            const float cf = coef[(size_t)row * E_NUM + e];
            bf16_t* hp = Hmid + (size_t)row * F_DIM + n0 + wn + fr;
#pragma unroll
            for (int ni = 0; ni < 4; ++ni) {
                const float s1 = acc1[mi][ni][r];
                const float s2 = acc2[mi][ni][r];
                const float val = (s1 / (1.f + __expf(-s1))) * s2 * cf;
                hp[ni * 16] = (bf16_t)val;
            }
        }
    }
}

// ---------------- GEMM2: Out (=/+=) Hmid @ W2  (W2 pre-transposed to [H,F] = [N,K]) ----------------
__global__ __launch_bounds__(256, 2)
void gemm2_out(const bf16_t* __restrict__ Hmid, const bf16_t* __restrict__ W2T,
               float* __restrict__ Out, int first) {
    __shared__ __attribute__((aligned(16))) bf16_t As[128 * 32];
    __shared__ __attribute__((aligned(16))) bf16_t Bs[128 * 32];
    const int tid = threadIdx.x;
    const int lane = tid & 63;
    const int wave = tid >> 6;
    const int m0 = blockIdx.x * 128;
    const int n0 = blockIdx.y * 128;
    const int wm = (wave >> 1) * 64;
    const int wn = (wave & 1) * 64;
    const int fr = lane & 15;
    const int q = lane >> 4;

    floatx4 acc[4][4];
    const floatx4 zero = {0.f, 0.f, 0.f, 0.f};
#pragma unroll
    for (int a = 0; a < 4; ++a)
#pragma unroll
        for (int b = 0; b < 4; ++b) acc[a][b] = zero;

    const int srow = tid >> 2;
    const int scc = (tid & 3) * 8;
    const int ldsb0 = (tid & 192) * 16;
    const int ldsb1 = 4096 + ldsb0;

    for (int k0 = 0; k0 < F_DIM; k0 += 32) {
        const size_t kc = (size_t)(k0 + scc);
        async_copy16(Hmid + (size_t)(m0 + srow) * F_DIM + kc, (char*)As + ldsb0);
        async_copy16(Hmid + (size_t)(m0 + 64 + srow) * F_DIM + kc, (char*)As + ldsb1);
        async_copy16(W2T + (size_t)(n0 + srow) * F_DIM + kc, (char*)Bs + ldsb0);
        async_copy16(W2T + (size_t)(n0 + 64 + srow) * F_DIM + kc, (char*)Bs + ldsb1);
        __syncthreads();

        bf16x8 af[4], bf[4];
#pragma unroll
        for (int mi = 0; mi < 4; ++mi)
            af[mi] = *(const bf16x8*)&As[(wm + mi * 16 + fr) * 32 + q * 8];
#pragma unroll
        for (int ni = 0; ni < 4; ++ni)
            bf[ni] = *(const bf16x8*)&Bs[(wn + ni * 16 + fr) * 32 + q * 8];
#pragma unroll
        for (int mi = 0; mi < 4; ++mi)
#pragma unroll
            for (int ni = 0; ni < 4; ++ni)
                acc[mi][ni] = __builtin_amdgcn_mfma_f32_16x16x32_bf16(af[mi], bf[ni], acc[mi][ni], 0, 0, 0);
        __syncthreads();
    }

#pragma unroll
    for (int mi = 0; mi < 4; ++mi) {
#pragma unroll
        for (int r = 0; r < 4; ++r) {
            const int row = m0 + wm + mi * 16 + q * 4 + r;
            float* op = Out + (size_t)row * H_DIM + n0 + wn + fr;
#pragma unroll
            for (int ni = 0; ni < 4; ++ni) {
                const float v = acc[mi][ni][r];
                if (first) op[ni * 16] = v;
                else op[ni * 16] += v;
            }
        }
    }
}

extern "C" void kernel_launch(void* const* d_in, const int* in_sizes, int n_in,
                              void* d_out, int out_size, void* d_ws, size_t ws_size,
                              hipStream_t stream) {
    const float* x  = (const float*)d_in[0];   // [T, H] fp32
    const float* rw = (const float*)d_in[1];   // [E, H] fp32
    const float* w1 = (const float*)d_in[2];   // [E, F, H] fp32
    const float* v1 = (const float*)d_in[3];   // [E, F, H] fp32
    const float* w2 = (const float*)d_in[4];   // [E, F, H] fp32
    float* out = (float*)d_out;                // [T, H] fp32

    // workspace carve-up (~252 MB)
    char* p = (char*)d_ws;
    bf16_t* xb   = (bf16_t*)p; p += (size_t)T_TOK * H_DIM * 2;
    bf16_t* w1b  = (bf16_t*)p; p += (size_t)E_NUM * F_DIM * H_DIM * 2;
    bf16_t* v1b  = (bf16_t*)p; p += (size_t)E_NUM * F_DIM * H_DIM * 2;
    bf16_t* w2t  = (bf16_t*)p; p += (size_t)E_NUM * F_DIM * H_DIM * 2;  // [E, H, F]
    bf16_t* hmid = (bf16_t*)p; p += (size_t)T_TOK * F_DIM * 2;          // reused per expert
    float*  coef = (float*)p;  p += (size_t)T_TOK * E_NUM * 4;

    const int nx4 = T_TOK * H_DIM / 4;
    const int nw4 = E_NUM * F_DIM * H_DIM / 4;
    cast_f32_to_bf16<<<nx4 / 256, 256, 0, stream>>>(x, xb, nx4);
    cast_f32_to_bf16<<<nw4 / 256, 256, 0, stream>>>(w1, w1b, nw4);
    cast_f32_to_bf16<<<nw4 / 256, 256, 0, stream>>>(v1, v1b, nw4);
    transpose_cast_w2<<<dim3(F_DIM / 32, H_DIM / 32, E_NUM), dim3(32, 8), 0, stream>>>(w2, w2t);
    router_kernel<<<T_TOK / 4, 256, 0, stream>>>(x, rw, coef);

    for (int e = 0; e < E_NUM; ++e) {
        const size_t off = (size_t)e * F_DIM * H_DIM;
        gemm1_glu<<<dim3(T_TOK / 128, F_DIM / 128), 256, 0, stream>>>(
            xb, w1b + off, v1b + off, coef, hmid, e);
        gemm2_out<<<dim3(T_TOK / 128, H_DIM / 128), 256, 0, stream>>>(
            hmid, w2t + off, out, e == 0 ? 1 : 0);
    }
}

// Round 2
// 926.520 us; speedup vs baseline: 2.7099x; 2.7099x over previous
//
#include <hip/hip_runtime.h>
#include <cstdint>
#include <cstddef>

// Problem constants (B=4, S=2048 -> T=8192 tokens)
#define T_TOK 8192
#define H_DIM 1024
#define F_DIM 3584
#define E_NUM 8
#define MAX_ROWS 17408   // 2T assignments + per-expert pad to 128
#define MAX_TILES 136    // ceil-sum of per-expert tiles, worst case

typedef __bf16 bf16_t;
typedef bf16_t bf16x8 __attribute__((ext_vector_type(8)));
typedef bf16_t bf16x4 __attribute__((ext_vector_type(4)));
typedef float floatx4 __attribute__((ext_vector_type(4)));

typedef const __attribute__((address_space(1))) void* gas_ptr;
typedef __attribute__((address_space(3))) void* las_ptr;

// async global->LDS, 16B per lane. LDS dest is wave-uniform base + lane*16;
// global address is per-lane (gather OK).
__device__ __forceinline__ void async_copy16(const void* g, void* l) {
    __builtin_amdgcn_global_load_lds((gas_ptr)g, (las_ptr)l, 16, 0, 0);
}

// ---------------- elementwise fp32 -> bf16 cast (4 elems/thread) ----------------
__global__ void cast_f32_to_bf16(const float* __restrict__ in, bf16_t* __restrict__ out, int n4) {
    int i = blockIdx.x * blockDim.x + threadIdx.x;
    if (i < n4) {
        const float4 v = ((const float4*)in)[i];
        bf16x4 o;
        o[0] = (bf16_t)v.x; o[1] = (bf16_t)v.y; o[2] = (bf16_t)v.z; o[3] = (bf16_t)v.w;
        ((bf16x4*)out)[i] = o;
    }
}

// ---------------- w2 [E,F,H] fp32 -> w2t [E,H,F] bf16 (tiled transpose) ----------------
__global__ void transpose_cast_w2(const float* __restrict__ W2, bf16_t* __restrict__ W2T) {
    __shared__ bf16_t tile[32][34];
    const int e = blockIdx.z;
    const int f0 = blockIdx.x * 32;
    const int h0 = blockIdx.y * 32;
    const float* src = W2 + (size_t)e * F_DIM * H_DIM;
    bf16_t* dst = W2T + (size_t)e * H_DIM * F_DIM;
    const int tx = threadIdx.x;  // 0..31
    const int ty = threadIdx.y;  // 0..7
#pragma unroll
    for (int r = 0; r < 32; r += 8)
        tile[ty + r][tx] = (bf16_t)src[(size_t)(f0 + ty + r) * H_DIM + (h0 + tx)];
    __syncthreads();
#pragma unroll
    for (int r = 0; r < 32; r += 8)
        dst[(size_t)(h0 + ty + r) * F_DIM + (f0 + tx)] = tile[tx][ty + r];
}

// ---------------- router: fp32 logits -> softmax -> top-2 -> renorm ----------------
// writes per-token: tok_e[t*2+{0,1}] expert ids (top1 first), tok_w renormalized weights
__global__ void router_kernel(const float* __restrict__ X, const float* __restrict__ RW,
                              int* __restrict__ tok_e, float* __restrict__ tok_w) {
    const int lane = threadIdx.x & 63;
    const int wave = threadIdx.x >> 6;
    const int t = blockIdx.x * 4 + wave;
    const float* xp = X + (size_t)t * H_DIM;
    float xr[16];
#pragma unroll
    for (int j = 0; j < 16; ++j) xr[j] = xp[j * 64 + lane];
    float logits[E_NUM];
#pragma unroll
    for (int e = 0; e < E_NUM; ++e) {
        const float* rp = RW + e * H_DIM;
        float a = 0.f;
#pragma unroll
        for (int j = 0; j < 16; ++j) a += xr[j] * rp[j * 64 + lane];
#pragma unroll
        for (int s = 32; s; s >>= 1) a += __shfl_xor(a, s, 64);
        logits[e] = a;
    }
    if (lane == 0) {
        float mx = logits[0];
#pragma unroll
        for (int e = 1; e < E_NUM; ++e) mx = fmaxf(mx, logits[e]);
        float p[E_NUM], sum = 0.f;
#pragma unroll
        for (int e = 0; e < E_NUM; ++e) { p[e] = __expf(logits[e] - mx); sum += p[e]; }
#pragma unroll
        for (int e = 0; e < E_NUM; ++e) p[e] /= sum;
        int i0 = 0;
#pragma unroll
        for (int e = 1; e < E_NUM; ++e) if (p[e] > p[i0]) i0 = e;  // ties -> lowest idx
        int i1 = (i0 == 0) ? 1 : 0;
#pragma unroll
        for (int e = 0; e < E_NUM; ++e) if (e != i0 && p[e] > p[i1]) i1 = e;
        const float s2 = p[i0] + p[i1];
        tok_e[t * 2 + 0] = i0; tok_w[t * 2 + 0] = p[i0] / s2;
        tok_e[t * 2 + 1] = i1; tok_w[t * 2 + 1] = p[i1] / s2;
    }
}

// ---------------- build per-expert assignment lists + tile metadata (1 block) ----------------
__global__ void build_assignments(const int* __restrict__ tok_e, const float* __restrict__ tok_w,
                                  int* __restrict__ asg_tok, float* __restrict__ asg_wt,
                                  int* __restrict__ tok_slot, int* __restrict__ tile_meta,
                                  int* __restrict__ n_tiles_out) {
    __shared__ int cnt[E_NUM];
    __shared__ int seg_start[E_NUM];
    __shared__ int seg_pad[E_NUM];
    const int tid = threadIdx.x;
    if (tid < E_NUM) cnt[tid] = 0;
    __syncthreads();
    for (int i = tid; i < T_TOK * 2; i += 1024) atomicAdd(&cnt[tok_e[i]], 1);
    __syncthreads();
    if (tid == 0) {
        int run = 0, nt = 0;
        for (int e = 0; e < E_NUM; ++e) {
            seg_start[e] = run;
            const int tiles = (cnt[e] + 127) >> 7;
            seg_pad[e] = tiles << 7;
            for (int j = 0; j < tiles; ++j) {
                tile_meta[nt * 2] = e;
                tile_meta[nt * 2 + 1] = run + j * 128;
                ++nt;
            }
            run += tiles << 7;
        }
        *n_tiles_out = nt;
    }
    __syncthreads();
    if (tid < E_NUM) cnt[tid] = 0;
    __syncthreads();
    for (int i = tid; i < T_TOK * 2; i += 1024) {
        const int e = tok_e[i];
        const int slot = atomicAdd(&cnt[e], 1);
        const int g = seg_start[e] + slot;
        asg_tok[g] = i >> 1;
        asg_wt[g] = tok_w[i];
        tok_slot[i] = g;
    }
    __syncthreads();
    for (int e = 0; e < E_NUM; ++e)
        for (int j = cnt[e] + tid; j < seg_pad[e]; j += 1024) {
            asg_tok[seg_start[e] + j] = -1;
            asg_wt[seg_start[e] + j] = 0.f;
        }
}

// LDS swizzle: global chunk q of tile row r lives at slot (q + (r>>1))&3 within the row.
// Staged chunk for staging thread: c = (slot - (srow>>1))&3 with slot = tid&3, srow = tid>>2.
// Fragment reads then hit each bank exactly 2x per 16-lane phase (2-way = free, m136).

// ---------------- grouped GEMM1 (dual-acc GLU): hmid[g] = wt * silu(x@w1^T) * (x@v1^T) ----------
__global__ __launch_bounds__(256, 2)
void gemm1_glu(const bf16_t* __restrict__ X, const bf16_t* __restrict__ W1all,
               const bf16_t* __restrict__ V1all, const int* __restrict__ asg_tok,
               const float* __restrict__ asg_wt, const int* __restrict__ tile_meta,
               const int* __restrict__ n_tiles, bf16_t* __restrict__ Hmid) {
    const int tile = blockIdx.x;
    if (tile >= *n_tiles) return;
    const int e = tile_meta[tile * 2];
    const int row0 = tile_meta[tile * 2 + 1];
    const bf16_t* W1 = W1all + (size_t)e * F_DIM * H_DIM;
    const bf16_t* V1 = V1all + (size_t)e * F_DIM * H_DIM;

    __shared__ __attribute__((aligned(16))) bf16_t As[128 * 32];
    __shared__ __attribute__((aligned(16))) bf16_t B1s[128 * 32];
    __shared__ __attribute__((aligned(16))) bf16_t B2s[128 * 32];
    const int tid = threadIdx.x;
    const int lane = tid & 63;
    const int wave = tid >> 6;
    const int n0 = blockIdx.y * 128;
    const int wm = (wave >> 1) * 64;
    const int wn = (wave & 1) * 64;
    const int fr = lane & 15;
    const int q = lane >> 4;

    floatx4 acc1[4][4], acc2[4][4];
    const floatx4 zero = {0.f, 0.f, 0.f, 0.f};
#pragma unroll
    for (int a = 0; a < 4; ++a)
#pragma unroll
        for (int b = 0; b < 4; ++b) { acc1[a][b] = zero; acc2[a][b] = zero; }

    const int srow = tid >> 2;
    const int c = ((tid & 3) - ((tid >> 3) & 3)) & 3;  // swizzled source chunk
    const int scc = c * 8;                             // bf16 column offset
    const int ldsb0 = (tid & 192) * 16;
    const int ldsb1 = 4096 + ldsb0;

    int t0 = asg_tok[row0 + srow];      if (t0 < 0) t0 = 0;
    int t1 = asg_tok[row0 + 64 + srow]; if (t1 < 0) t1 = 0;
    const bf16_t* a0p = X + (size_t)t0 * H_DIM + scc;
    const bf16_t* a1p = X + (size_t)t1 * H_DIM + scc;
    const bf16_t* b1p0 = W1 + (size_t)(n0 + srow) * H_DIM + scc;
    const bf16_t* b1p1 = W1 + (size_t)(n0 + 64 + srow) * H_DIM + scc;
    const bf16_t* b2p0 = V1 + (size_t)(n0 + srow) * H_DIM + scc;
    const bf16_t* b2p1 = V1 + (size_t)(n0 + 64 + srow) * H_DIM + scc;

    for (int k0 = 0; k0 < H_DIM; k0 += 32) {
        async_copy16(a0p + k0, (char*)As + ldsb0);
        async_copy16(a1p + k0, (char*)As + ldsb1);
        async_copy16(b1p0 + k0, (char*)B1s + ldsb0);
        async_copy16(b1p1 + k0, (char*)B1s + ldsb1);
        async_copy16(b2p0 + k0, (char*)B2s + ldsb0);
        async_copy16(b2p1 + k0, (char*)B2s + ldsb1);
        __syncthreads();

        bf16x8 af[4], b1f[4], b2f[4];
#pragma unroll
        for (int mi = 0; mi < 4; ++mi) {
            const int r = wm + mi * 16 + fr;
            const int sl = (q + ((r >> 1) & 3)) & 3;
            af[mi] = *(const bf16x8*)&As[r * 32 + sl * 8];
        }
#pragma unroll
        for (int ni = 0; ni < 4; ++ni) {
            const int r = wn + ni * 16 + fr;
            const int sl = (q + ((r >> 1) & 3)) & 3;
            b1f[ni] = *(const bf16x8*)&B1s[r * 32 + sl * 8];
            b2f[ni] = *(const bf16x8*)&B2s[r * 32 + sl * 8];
        }
#pragma unroll
        for (int mi = 0; mi < 4; ++mi)
#pragma unroll
            for (int ni = 0; ni < 4; ++ni) {
                acc1[mi][ni] = __builtin_amdgcn_mfma_f32_16x16x32_bf16(af[mi], b1f[ni], acc1[mi][ni], 0, 0, 0);
                acc2[mi][ni] = __builtin_amdgcn_mfma_f32_16x16x32_bf16(af[mi], b2f[ni], acc2[mi][ni], 0, 0, 0);
            }
        __syncthreads();
    }

    // epilogue: C layout col = lane&15, row = q*4 + reg
#pragma unroll
    for (int mi = 0; mi < 4; ++mi) {
#pragma unroll
        for (int r = 0; r < 4; ++r) {
            const int gr = row0 + wm + mi * 16 + q * 4 + r;
            const float wt = asg_wt[gr];
            bf16_t* hp = Hmid + (size_t)gr * F_DIM + n0 + wn + fr;
#pragma unroll
            for (int ni = 0; ni < 4; ++ni) {
                const float s1 = acc1[mi][ni][r];
                const float s2 = acc2[mi][ni][r];
                const float val = (s1 / (1.f + __expf(-s1))) * s2 * wt;
                hp[ni * 16] = (bf16_t)val;
            }
        }
    }
}

// ---------------- grouped GEMM2: oasm[g] = hmid[g] @ W2[e]  (fp32 out per assignment) --------
__global__ __launch_bounds__(256, 2)
void gemm2_out(const bf16_t* __restrict__ Hmid, const bf16_t* __restrict__ W2Tall,
               const int* __restrict__ tile_meta, const int* __restrict__ n_tiles,
               float* __restrict__ Oasm) {
    const int tile = blockIdx.x;
    if (tile >= *n_tiles) return;
    const int e = tile_meta[tile * 2];
    const int row0 = tile_meta[tile * 2 + 1];
    const bf16_t* W2T = W2Tall + (size_t)e * H_DIM * F_DIM;

    __shared__ __attribute__((aligned(16))) bf16_t As[128 * 32];
    __shared__ __attribute__((aligned(16))) bf16_t Bs[128 * 32];
    const int tid = threadIdx.x;
    const int lane = tid & 63;
    const int wave = tid >> 6;
    const int n0 = blockIdx.y * 128;
    const int wm = (wave >> 1) * 64;
    const int wn = (wave & 1) * 64;
    const int fr = lane & 15;
    const int q = lane >> 4;

    floatx4 acc[4][4];
    const floatx4 zero = {0.f, 0.f, 0.f, 0.f};
#pragma unroll
    for (int a = 0; a < 4; ++a)
#pragma unroll
        for (int b = 0; b < 4; ++b) acc[a][b] = zero;

    const int srow = tid >> 2;
    const int c = ((tid & 3) - ((tid >> 3) & 3)) & 3;
    const int scc = c * 8;
    const int ldsb0 = (tid & 192) * 16;
    const int ldsb1 = 4096 + ldsb0;

    const bf16_t* a0p = Hmid + (size_t)(row0 + srow) * F_DIM + scc;
    const bf16_t* a1p = Hmid + (size_t)(row0 + 64 + srow) * F_DIM + scc;
    const bf16_t* b0p = W2T + (size_t)(n0 + srow) * F_DIM + scc;
    const bf16_t* b1p = W2T + (size_t)(n0 + 64 + srow) * F_DIM + scc;

    for (int k0 = 0; k0 < F_DIM; k0 += 32) {
        async_copy16(a0p + k0, (char*)As + ldsb0);
        async_copy16(a1p + k0, (char*)As + ldsb1);
        async_copy16(b0p + k0, (char*)Bs + ldsb0);
        async_copy16(b1p + k0, (char*)Bs + ldsb1);
        __syncthreads();

        bf16x8 af[4], bf[4];
#pragma unroll
        for (int mi = 0; mi < 4; ++mi) {
            const int r = wm + mi * 16 + fr;
            const int sl = (q + ((r >> 1) & 3)) & 3;
            af[mi] = *(const bf16x8*)&As[r * 32 + sl * 8];
        }
#pragma unroll
        for (int ni = 0; ni < 4; ++ni) {
            const int r = wn + ni * 16 + fr;
            const int sl = (q + ((r >> 1) & 3)) & 3;
            bf[ni] = *(const bf16x8*)&Bs[r * 32 + sl * 8];
        }
#pragma unroll
        for (int mi = 0; mi < 4; ++mi)
#pragma unroll
            for (int ni = 0; ni < 4; ++ni)
                acc[mi][ni] = __builtin_amdgcn_mfma_f32_16x16x32_bf16(af[mi], bf[ni], acc[mi][ni], 0, 0, 0);
        __syncthreads();
    }

#pragma unroll
    for (int mi = 0; mi < 4; ++mi) {
#pragma unroll
        for (int r = 0; r < 4; ++r) {
            const int gr = row0 + wm + mi * 16 + q * 4 + r;
            float* op = Oasm + (size_t)gr * H_DIM + n0 + wn + fr;
#pragma unroll
            for (int ni = 0; ni < 4; ++ni)
                op[ni * 16] = acc[mi][ni][r];
        }
    }
}

// ---------------- combine: out[t] = oasm[slot0(t)] + oasm[slot1(t)]  (deterministic) ---------
__global__ void combine_kernel(const float* __restrict__ Oasm, const int* __restrict__ tok_slot,
                               float* __restrict__ Out) {
    const int t = blockIdx.x;
    const int s0 = tok_slot[t * 2];
    const int s1 = tok_slot[t * 2 + 1];
    const float4 v0 = ((const float4*)(Oasm + (size_t)s0 * H_DIM))[threadIdx.x];
    const float4 v1 = ((const float4*)(Oasm + (size_t)s1 * H_DIM))[threadIdx.x];
    float4 o; o.x = v0.x + v1.x; o.y = v0.y + v1.y; o.z = v0.z + v1.z; o.w = v0.w + v1.w;
    ((float4*)(Out + (size_t)t * H_DIM))[threadIdx.x] = o;
}

extern "C" void kernel_launch(void* const* d_in, const int* in_sizes, int n_in,
                              void* d_out, int out_size, void* d_ws, size_t ws_size,
                              hipStream_t stream) {
    const float* x  = (const float*)d_in[0];   // [T, H] fp32
    const float* rw = (const float*)d_in[1];   // [E, H] fp32
    const float* w1 = (const float*)d_in[2];   // [E, F, H] fp32
    const float* v1 = (const float*)d_in[3];   // [E, F, H] fp32
    const float* w2 = (const float*)d_in[4];   // [E, F, H] fp32
    float* out = (float*)d_out;                // [T, H] fp32

    // workspace layout (byte offsets). Phase-1 live: xb, w1b, v1b, hmid.
    // Phase-2 live: w2t (aliases xb + w1b head), oasm (aliases w1b tail + v1b), hmid.
    char* ws = (char*)d_ws;
    const size_t MB = 1024 * 1024;
    bf16_t* xb   = (bf16_t*)(ws + 0);          // 16 MiB [0, 16)
    bf16_t* w1b  = (bf16_t*)(ws + 16 * MB);    // 56 MiB [16, 72)
    bf16_t* v1b  = (bf16_t*)(ws + 72 * MB);    // 56 MiB [72, 128)
    bf16_t* hmid = (bf16_t*)(ws + 128 * MB);   // 119 MiB [128, 247.01)
    bf16_t* w2t  = (bf16_t*)(ws + 0);          // 56 MiB [0, 56)   (after gemm1)
    float*  oasm = (float*)(ws + 56 * MB);     // 68 MiB [56, 124) (after gemm1)
    char* meta = ws + 128 * MB + (size_t)MAX_ROWS * F_DIM * 2;
    int*   asg_tok  = (int*)meta;                meta += MAX_ROWS * 4;
    float* asg_wt   = (float*)meta;              meta += MAX_ROWS * 4;
    int*   tok_slot = (int*)meta;                meta += T_TOK * 2 * 4;
    int*   tok_e    = (int*)meta;                meta += T_TOK * 2 * 4;
    float* tok_w    = (float*)meta;              meta += T_TOK * 2 * 4;
    int*   tile_meta = (int*)meta;               meta += MAX_TILES * 2 * 4;
    int*   n_tiles   = (int*)meta;               meta += 4;

    const int nx4 = T_TOK * H_DIM / 4;
    const int nw4 = E_NUM * F_DIM * H_DIM / 4;
    cast_f32_to_bf16<<<nx4 / 256, 256, 0, stream>>>(x, xb, nx4);
    cast_f32_to_bf16<<<nw4 / 256, 256, 0, stream>>>(w1, w1b, nw4);
    cast_f32_to_bf16<<<nw4 / 256, 256, 0, stream>>>(v1, v1b, nw4);
    router_kernel<<<T_TOK / 4, 256, 0, stream>>>(x, rw, tok_e, tok_w);
    build_assignments<<<1, 1024, 0, stream>>>(tok_e, tok_w, asg_tok, asg_wt,
                                              tok_slot, tile_meta, n_tiles);
    gemm1_glu<<<dim3(MAX_TILES, F_DIM / 128), 256, 0, stream>>>(
        xb, w1b, v1b, asg_tok, asg_wt, tile_meta, n_tiles, hmid);
    // w1b/v1b/xb dead from here; build w2t over them
    transpose_cast_w2<<<dim3(F_DIM / 32, H_DIM / 32, E_NUM), dim3(32, 8), 0, stream>>>(w2, w2t);
    gemm2_out<<<dim3(MAX_TILES, H_DIM / 128), 256, 0, stream>>>(
        hmid, w2t, tile_meta, n_tiles, oasm);
    combine_kernel<<<T_TOK, 256, 0, stream>>>(oasm, tok_slot, out);
}